// Round 1
// 296.753 us; speedup vs baseline: 1.1192x; 1.1192x over previous
//
#include <hip/hip_runtime.h>

// Problem constants
#define B_SZ 512
#define C_CH 256
#define L_SEQ 256
#define H_DIM 512
#define T_STEP 16
#define W_WIN 8
#define NSLAB 24   // max distinct l values = T+W-1 = 23, round up
#define NCE_SHIFT 40.0f

typedef __attribute__((ext_vector_type(8))) short short8;
typedef __attribute__((ext_vector_type(4))) float f32x4;

#define GLOBAL_U32 const __attribute__((address_space(1))) unsigned int*
#define LDS_U32 __attribute__((address_space(3))) unsigned int*
// async 16B/lane global->LDS; LDS dest = wave-uniform base + lane*16
#define ASYNC_COPY16(g, l) \
  __builtin_amdgcn_global_load_lds((GLOBAL_U32)(const void*)(g), (LDS_U32)(void*)(l), 16, 0, 0)

__device__ inline unsigned short f2bf(float x) {  // RNE f32 -> bf16
  unsigned u = __float_as_uint(x);
  u = (u + 0x7FFFu + ((u >> 16) & 1u)) >> 16;
  return (unsigned short)u;
}

// ---------------- fused prep: 3 casts + zero bnp1/bnp2/out[0] ----------------
// blocks 0..2047: ct (2M elems), 2048..4095: wk (2M), 4096..4159: pw1 (64K), 4160: zeroing
__global__ __launch_bounds__(256) void prep(const float* __restrict__ ct,
                                            const float* __restrict__ wk,
                                            const float* __restrict__ pw1,
                                            unsigned short* __restrict__ ctb,
                                            unsigned short* __restrict__ wkb,
                                            unsigned short* __restrict__ pw1b,
                                            float* __restrict__ bnp1,
                                            float* __restrict__ bnp2,
                                            float* __restrict__ out) {
  int b = blockIdx.x;
  if (b == 4160) {
    if (threadIdx.x < 128) { bnp1[threadIdx.x] = 0.f; bnp2[threadIdx.x] = 0.f; }
    if (threadIdx.x == 0) out[0] = 0.f;
    return;
  }
  const float* s;
  unsigned short* d;
  int base;
  if (b < 2048)      { s = ct;  d = ctb;  base = b * 1024; }
  else if (b < 4096) { s = wk;  d = wkb;  base = (b - 2048) * 1024; }
  else               { s = pw1; d = pw1b; base = (b - 4096) * 1024; }
  int i = base + threadIdx.x * 4;
  float4 v = ((const float4*)s)[i >> 2];
  ushort4 o;
  o.x = f2bf(v.x); o.y = f2bf(v.y); o.z = f2bf(v.z); o.w = f2bf(v.w);
  ((ushort4*)d)[i >> 2] = o;
}

// ---------------- encode slabs: F[l'][b][c] = bf16(features[b][c][lmin+l']) ----------------
__global__ __launch_bounds__(256) void build_slabs2(const float* __restrict__ f,
                                                    unsigned short* __restrict__ F,
                                                    const int* __restrict__ tsp) {
  const int ts = tsp[0];
  const int lmin = min(ts + 1, L_SEQ - W_WIN);
  const int b = blockIdx.x;
  const int c = threadIdx.x;
  const float* src = f + ((size_t)b * C_CH + c) * L_SEQ;
  float v[NSLAB];
#pragma unroll
  for (int lp = 0; lp < NSLAB; lp++) {
    int l = lmin + lp;
    v[lp] = (l < L_SEQ) ? src[l] : 0.f;
  }
#pragma unroll
  for (int lp = 0; lp < NSLAB; lp++)
    F[((size_t)lp * B_SZ + b) * C_CH + c] = f2bf(v[lp]);
}

// ---------------- bf16 MFMA GEMM: D = A[M,K] * Bt[N,K]^T + bias[col] ----------------
// MODE 0: pred GEMM (M=N=4096), XCD-swizzled grid 1024, bf16 out in [t][w][a][c]
// MODE 1: h1 GEMM (M=4096,N=128), grid 32, f32 out + BN stage-1 partial sums (atomics)
template <int MODE>
__global__ __launch_bounds__(256) void gemm_bt(const unsigned short* __restrict__ A,
                                               const unsigned short* __restrict__ Bt,
                                               const float* __restrict__ bias,
                                               unsigned short* __restrict__ outb,
                                               float* __restrict__ outf,
                                               float* __restrict__ bnp1,
                                               float* __restrict__ bnp2, int K) {
  __shared__ __align__(16) unsigned short As[128 * 64];
  __shared__ __align__(16) unsigned short Bs[128 * 64];
  const int tid = threadIdx.x;
  const int wv = tid >> 6, lane = tid & 63, quad = lane >> 4, l15 = lane & 15;
  const int wm = wv >> 1, wn = wv & 1;
  int M0, N0;
  if (MODE == 0) {
    // bijective XCD swizzle: each XCD gets 4 M-panels x all 32 N-panels
    int swz = (blockIdx.x & 7) * 128 + (blockIdx.x >> 3);
    M0 = (swz >> 5) * 128;
    N0 = (swz & 31) * 128;
  } else {
    M0 = blockIdx.x * 128;
    N0 = 0;
  }

  f32x4 acc[4][4];
#pragma unroll
  for (int i = 0; i < 4; i++)
#pragma unroll
    for (int j = 0; j < 4; j++) acc[i][j] = (f32x4){0.f, 0.f, 0.f, 0.f};

  for (int k0 = 0; k0 < K; k0 += 64) {
#pragma unroll
    for (int i = 0; i < 4; i++) {
      int chunk = (i * 4 + wv) * 64 + lane;      // 1024 chunks of 16B = [128][64] bf16 tile
      int row = chunk >> 3, off = chunk & 7;     // 8 chunks per 128B row
      const unsigned short* ga = A + (size_t)(M0 + row) * K + k0 + off * 8;
      const unsigned short* gb = Bt + (size_t)(N0 + row) * K + k0 + off * 8;
      ASYNC_COPY16(ga, &As[(size_t)(i * 4 + wv) * 512]);
      ASYNC_COPY16(gb, &Bs[(size_t)(i * 4 + wv) * 512]);
    }
    __syncthreads();  // drains vmcnt
#pragma unroll
    for (int kk = 0; kk < 64; kk += 32) {
      short8 af[4], bfr[4];
#pragma unroll
      for (int i = 0; i < 4; i++)
        af[i] = *(const short8*)&As[(wm * 64 + i * 16 + l15) * 64 + kk + quad * 8];
#pragma unroll
      for (int j = 0; j < 4; j++)
        bfr[j] = *(const short8*)&Bs[(wn * 64 + j * 16 + l15) * 64 + kk + quad * 8];
#pragma unroll
      for (int i = 0; i < 4; i++)
#pragma unroll
        for (int j = 0; j < 4; j++)
          acc[i][j] = __builtin_amdgcn_mfma_f32_16x16x32_bf16(af[i], bfr[j], acc[i][j], 0, 0, 0);
    }
    __syncthreads();
  }

  // epilogue: D mapping col=lane&15, row=quad*4+reg (m89/m91-verified)
  float st1[4], st2[4];
#pragma unroll
  for (int j = 0; j < 4; j++) { st1[j] = 0.f; st2[j] = 0.f; }
#pragma unroll
  for (int i = 0; i < 4; i++) {
    int rbase = M0 + wm * 64 + i * 16 + quad * 4;
#pragma unroll
    for (int j = 0; j < 4; j++) {
      int cc = N0 + wn * 64 + j * 16 + l15;
      float bv = bias[cc];
#pragma unroll
      for (int r = 0; r < 4; r++) {
        int rr = rbase + r;
        float v = acc[i][j][r] + bv;
        if (MODE == 0) {
          int t = cc >> 8, c = cc & 255, a = rr >> 3, w_ = rr & 7;
          outb[((size_t)(t * 8 + w_) * 512 + a) * 256 + c] = f2bf(v);
        } else {
          outf[(size_t)rr * 128 + cc] = v;
          st1[j] += v;
          st2[j] += v * v;
        }
      }
    }
  }
  if (MODE == 1) {
    // BN stage-1: reduce per-column sums within block, one atomic per column
    __shared__ float red1[2][128], red2[2][128];
#pragma unroll
    for (int j = 0; j < 4; j++) {
      float a1 = st1[j], a2 = st2[j];
      a1 += __shfl_xor(a1, 16); a1 += __shfl_xor(a1, 32);
      a2 += __shfl_xor(a2, 16); a2 += __shfl_xor(a2, 32);
      if (quad == 0) {
        red1[wm][wn * 64 + j * 16 + l15] = a1;
        red2[wm][wn * 64 + j * 16 + l15] = a2;
      }
    }
    __syncthreads();
    if (tid < 128) {
      atomicAdd(&bnp1[tid], red1[0][tid] + red1[1][tid]);
      atomicAdd(&bnp2[tid], red2[0][tid] + red2[1][tid]);
    }
  }
}

// ---------------- scores GEMM tile + exp-sum/diag epilogue ----------------
// linear grid 2048, XCD-swizzled so each XCD owns 16 consecutive tw (pred/slab L2 locality).
// No atomics: per-(colblk,wn) partials stored to rowsum_p[tw][8][512].
__global__ __launch_bounds__(256) void scores_gemm(const unsigned short* __restrict__ F,
                                                   const unsigned short* __restrict__ pred,
                                                   const int* __restrict__ tsp,
                                                   float* __restrict__ rowsum_p,
                                                   float* __restrict__ diagv) {
  __shared__ __align__(16) unsigned short As[128 * 64];
  __shared__ __align__(16) unsigned short Bs[128 * 64];
  const int tid = threadIdx.x;
  const int wv = tid >> 6, lane = tid & 63, quad = lane >> 4, l15 = lane & 15;
  const int wm = wv >> 1, wn = wv & 1;
  const int swz = (blockIdx.x & 7) * 256 + (blockIdx.x >> 3);  // bijective, 2048%8==0
  const int tw = swz >> 4, rowblk = (swz >> 2) & 3, colblk = swz & 3;
  const int t = tw >> 3, w_ = tw & 7;
  const int ts = tsp[0];
  const int lmin = min(ts + 1, L_SEQ - W_WIN);
  const int lp = min(ts + 1 + t, L_SEQ - W_WIN) + w_ - lmin;
  const unsigned short* A = F + (size_t)lp * (B_SZ * C_CH) + (size_t)rowblk * 128 * C_CH;
  const unsigned short* Bt = pred + (size_t)tw * (B_SZ * C_CH) + (size_t)colblk * 128 * C_CH;

  f32x4 acc[4][4];
#pragma unroll
  for (int i = 0; i < 4; i++)
#pragma unroll
    for (int j = 0; j < 4; j++) acc[i][j] = (f32x4){0.f, 0.f, 0.f, 0.f};

  for (int k0 = 0; k0 < C_CH; k0 += 64) {
#pragma unroll
    for (int i = 0; i < 4; i++) {
      int chunk = (i * 4 + wv) * 64 + lane;
      int row = chunk >> 3, off = chunk & 7;
      ASYNC_COPY16(A + (size_t)row * C_CH + k0 + off * 8, &As[(size_t)(i * 4 + wv) * 512]);
      ASYNC_COPY16(Bt + (size_t)row * C_CH + k0 + off * 8, &Bs[(size_t)(i * 4 + wv) * 512]);
    }
    __syncthreads();
#pragma unroll
    for (int kk = 0; kk < 64; kk += 32) {
      short8 af[4], bfr[4];
#pragma unroll
      for (int i = 0; i < 4; i++)
        af[i] = *(const short8*)&As[(wm * 64 + i * 16 + l15) * 64 + kk + quad * 8];
#pragma unroll
      for (int j = 0; j < 4; j++)
        bfr[j] = *(const short8*)&Bs[(wn * 64 + j * 16 + l15) * 64 + kk + quad * 8];
#pragma unroll
      for (int i = 0; i < 4; i++)
#pragma unroll
        for (int j = 0; j < 4; j++)
          acc[i][j] = __builtin_amdgcn_mfma_f32_16x16x32_bf16(af[i], bfr[j], acc[i][j], 0, 0, 0);
    }
    __syncthreads();
  }

  // epilogue: per-row (b) partial sum of exp over this wave's 64 cols -> direct store
#pragma unroll
  for (int i = 0; i < 4; i++) {
#pragma unroll
    for (int r = 0; r < 4; r++) {
      float e = 0.f;
#pragma unroll
      for (int j = 0; j < 4; j++) e += __expf(acc[i][j][r] - NCE_SHIFT);
      e += __shfl_xor(e, 1);
      e += __shfl_xor(e, 2);
      e += __shfl_xor(e, 4);
      e += __shfl_xor(e, 8);
      if (l15 == 0) {
        int b = rowblk * 128 + wm * 64 + i * 16 + quad * 4 + r;
        rowsum_p[((size_t)tw * 8 + colblk * 2 + wn) * B_SZ + b] = e;
      }
    }
  }
  if (rowblk == colblk && wm == wn) {
#pragma unroll
    for (int i = 0; i < 4; i++)
#pragma unroll
      for (int r = 0; r < 4; r++)
        if (l15 == quad * 4 + r) {
          int b = rowblk * 128 + wm * 64 + i * 16 + quad * 4 + r;
          diagv[(size_t)tw * B_SZ + b] = acc[i][i][r];
        }
  }
}

// ---------------- nce reduction over 65536 rows (fused final sum via atomic) ----------------
__global__ __launch_bounds__(256) void nce_rows(const float* __restrict__ rowsum_p,
                                                const float* __restrict__ diagv,
                                                float* __restrict__ out) {
  int gid = blockIdx.x * 256 + threadIdx.x;  // 16384 threads
  float s = 0.f;
  for (int i = gid; i < 65536; i += 16384) {
    int tw = i >> 9, b = i & 511;
    float rs = 0.f;
#pragma unroll
    for (int p = 0; p < 8; p++) rs += rowsum_p[((size_t)tw * 8 + p) * B_SZ + b];
    s += logf(rs) + NCE_SHIFT - diagv[i];  // = -logp_diag
  }
#pragma unroll
  for (int off = 1; off < 64; off <<= 1) s += __shfl_xor(s, off);
  __shared__ float r[4];
  if ((threadIdx.x & 63) == 0) r[threadIdx.x >> 6] = s;
  __syncthreads();
  if (threadIdx.x == 0)
    atomicAdd(out, (r[0] + r[1] + r[2] + r[3]) * (1.f / 65536.f));
}

// ---------------- BN-finalize + apply + ReLU + GEMM2 -> proj (fp32, register-tiled) ----------------
// grid 64 blocks x 256 threads; block = 64 rows x 64 cols, thread = 4x4 register tile.
__global__ __launch_bounds__(256) void proj2(const float* __restrict__ h1,
                                             const float* __restrict__ bnp1,
                                             const float* __restrict__ bnp2,
                                             const float* __restrict__ g,
                                             const float* __restrict__ bta,
                                             const float* __restrict__ pw2,
                                             const float* __restrict__ pb2,
                                             float* __restrict__ out) {
  __shared__ float hsT[128][68];   // [k][row], pad 68 keeps 16B-aligned rows, no read conflicts
  __shared__ float pw2T[128][68];  // [k][col]
  __shared__ float scs[128], shs[128];
  const int tid = threadIdx.x;
  // stage pw2 transposed
  for (int idx = tid; idx < 64 * 128; idx += 256) {
    int oc = idx >> 7, k = idx & 127;
    pw2T[k][oc] = pw2[idx];
  }
  if (tid < 128) {
    float mean = bnp1[tid] * (1.f / 4096.f);
    float var = bnp2[tid] * (1.f / 4096.f) - mean * mean;  // biased (BN train)
    float scale = g[tid] * rsqrtf(var + 1e-5f);
    scs[tid] = scale;
    shs[tid] = bta[tid] - mean * scale;
  }
  __syncthreads();
  const int r0 = blockIdx.x * 64;
  for (int idx = tid; idx < 64 * 128; idx += 256) {
    int r = idx >> 7, k = idx & 127;
    float v = h1[(size_t)(r0 + r) * 128 + k];
    hsT[k][r] = fmaxf(v * scs[k] + shs[k], 0.f);  // BN apply + ReLU, transposed store
  }
  __syncthreads();
  const int tx = tid & 15, ty = tid >> 4;  // 16x16 thread grid, 4x4 outputs each
  float acc[4][4] = {};
  for (int k = 0; k < 128; k++) {
    f32x4 hv = *(const f32x4*)&hsT[k][ty * 4];
    f32x4 wv = *(const f32x4*)&pw2T[k][tx * 4];
#pragma unroll
    for (int i = 0; i < 4; i++)
#pragma unroll
      for (int j = 0; j < 4; j++) acc[i][j] += hv[i] * wv[j];
  }
#pragma unroll
  for (int i = 0; i < 4; i++) {
    int rr = r0 + ty * 4 + i;
#pragma unroll
    for (int j = 0; j < 4; j++)
      out[(size_t)rr * 64 + tx * 4 + j] = acc[i][j] + pb2[tx * 4 + j];
  }
}

extern "C" void kernel_launch(void* const* d_in, const int* in_sizes, int n_in,
                              void* d_out, int out_size, void* d_ws, size_t ws_size,
                              hipStream_t stream) {
  const float* features = (const float*)d_in[0];
  const float* c_t      = (const float*)d_in[1];
  const float* Wk_w     = (const float*)d_in[2];
  const float* Wk_b     = (const float*)d_in[3];
  const float* pw1      = (const float*)d_in[4];
  const float* pb1      = (const float*)d_in[5];
  const float* bn_gamma = (const float*)d_in[6];
  const float* bn_beta  = (const float*)d_in[7];
  const float* pw2      = (const float*)d_in[8];
  const float* pb2      = (const float*)d_in[9];
  const int*   tsp      = (const int*)d_in[10];
  float* out = (float*)d_out;

  // workspace carve-up (~52 MB total)
  char* ws = (char*)d_ws;
  size_t off = 0;
  auto carve = [&](size_t bytes) { void* p = ws + off; off += (bytes + 255) & ~(size_t)255; return p; };
  unsigned short* ct_bf  = (unsigned short*)carve((size_t)4096 * 512 * 2);   // c_t bf16 [bw][h]
  unsigned short* wk_bf  = (unsigned short*)carve((size_t)4096 * 512 * 2);   // Wk bf16 [tc][h]
  unsigned short* pw1_bf = (unsigned short*)carve((size_t)128 * 512 * 2);
  unsigned short* F      = (unsigned short*)carve((size_t)NSLAB * 512 * 256 * 2);
  unsigned short* pred   = (unsigned short*)carve((size_t)16 * 8 * 512 * 256 * 2);
  float* h1       = (float*)carve((size_t)4096 * 128 * 4);
  float* bnp1     = (float*)carve((size_t)128 * 4);
  float* bnp2     = (float*)carve((size_t)128 * 4);
  float* rowsum_p = (float*)carve((size_t)128 * 8 * 512 * 4);
  float* diagv    = (float*)carve((size_t)65536 * 4);

  // fused casts + zero bn partials + zero out[0]
  prep<<<4161, 256, 0, stream>>>(c_t, Wk_w, pw1, ct_bf, wk_bf, pw1_bf, bnp1, bnp2, out);
  build_slabs2<<<512, 256, 0, stream>>>(features, F, tsp);

  // pred[t][w][a][c] = c_t @ Wk^T + Wk_b   (M=N=4096, K=512), XCD-swizzled
  gemm_bt<0><<<1024, 256, 0, stream>>>(ct_bf, wk_bf, Wk_b, pred, nullptr, nullptr, nullptr, 512);
  // h1 = c_t2d @ pw1^T + pb1   (M=4096, N=128, K=512) + BN stage-1 partials
  gemm_bt<1><<<32, 256, 0, stream>>>(ct_bf, pw1_bf, pb1, nullptr, h1, bnp1, bnp2, 512);

  scores_gemm<<<2048, 256, 0, stream>>>(F, pred, tsp, rowsum_p, diagv);
  nce_rows<<<64, 256, 0, stream>>>(rowsum_p, diagv, out);

  proj2<<<64, 256, 0, stream>>>(h1, bnp1, bnp2, bn_gamma, bn_beta, pw2, pb2, out + 1);
}

// Round 2
// 287.205 us; speedup vs baseline: 1.1564x; 1.0332x over previous
//
#include <hip/hip_runtime.h>

// Problem constants
#define B_SZ 512
#define C_CH 256
#define L_SEQ 256
#define H_DIM 512
#define T_STEP 16
#define W_WIN 8
#define NSLAB 24   // max distinct l values = T+W-1 = 23, round up
#define NCE_SHIFT 40.0f

typedef __attribute__((ext_vector_type(8))) short short8;
typedef __attribute__((ext_vector_type(4))) float f32x4;

#define GLOBAL_U32 const __attribute__((address_space(1))) unsigned int*
#define LDS_U32 __attribute__((address_space(3))) unsigned int*
// async 16B/lane global->LDS; LDS dest = wave-uniform base + lane*16
#define ASYNC_COPY16(g, l) \
  __builtin_amdgcn_global_load_lds((GLOBAL_U32)(const void*)(g), (LDS_U32)(void*)(l), 16, 0, 0)

#define BARRIER __builtin_amdgcn_s_barrier()
#define SCHEDB  __builtin_amdgcn_sched_barrier(0)
// rule 18: lgkmcnt(0) must be followed by sched_barrier(0) or MFMA hoists past it
#define LGK0 do { asm volatile("s_waitcnt lgkmcnt(0)" ::: "memory"); __builtin_amdgcn_sched_barrier(0); } while (0)

__device__ inline unsigned short f2bf(float x) {  // RNE f32 -> bf16
  unsigned u = __float_as_uint(x);
  u = (u + 0x7FFFu + ((u >> 16) & 1u)) >> 16;
  return (unsigned short)u;
}

// ---------------- fused prep: 3 casts + zero bnp1/bnp2/out[0] ----------------
__global__ __launch_bounds__(256) void prep(const float* __restrict__ ct,
                                            const float* __restrict__ wk,
                                            const float* __restrict__ pw1,
                                            unsigned short* __restrict__ ctb,
                                            unsigned short* __restrict__ wkb,
                                            unsigned short* __restrict__ pw1b,
                                            float* __restrict__ bnp1,
                                            float* __restrict__ bnp2,
                                            float* __restrict__ out) {
  int b = blockIdx.x;
  if (b == 4160) {
    if (threadIdx.x < 128) { bnp1[threadIdx.x] = 0.f; bnp2[threadIdx.x] = 0.f; }
    if (threadIdx.x == 0) out[0] = 0.f;
    return;
  }
  const float* s;
  unsigned short* d;
  int base;
  if (b < 2048)      { s = ct;  d = ctb;  base = b * 1024; }
  else if (b < 4096) { s = wk;  d = wkb;  base = (b - 2048) * 1024; }
  else               { s = pw1; d = pw1b; base = (b - 4096) * 1024; }
  int i = base + threadIdx.x * 4;
  float4 v = ((const float4*)s)[i >> 2];
  ushort4 o;
  o.x = f2bf(v.x); o.y = f2bf(v.y); o.z = f2bf(v.z); o.w = f2bf(v.w);
  ((ushort4*)d)[i >> 2] = o;
}

// ---------------- encode slabs: F[l'][b][c] = bf16(features[b][c][lmin+l']) ----------------
__global__ __launch_bounds__(256) void build_slabs2(const float* __restrict__ f,
                                                    unsigned short* __restrict__ F,
                                                    const int* __restrict__ tsp) {
  const int ts = tsp[0];
  const int lmin = min(ts + 1, L_SEQ - W_WIN);
  const int b = blockIdx.x;
  const int c = threadIdx.x;
  const float* src = f + ((size_t)b * C_CH + c) * L_SEQ;
  float v[NSLAB];
#pragma unroll
  for (int lp = 0; lp < NSLAB; lp++) {
    int l = lmin + lp;
    v[lp] = (l < L_SEQ) ? src[l] : 0.f;
  }
#pragma unroll
  for (int lp = 0; lp < NSLAB; lp++)
    F[((size_t)lp * B_SZ + b) * C_CH + c] = f2bf(v[lp]);
}

// =============== 256x256 8-phase bf16 GEMM core (T3+T4+T5, chunk-XOR swizzle) ===============
// 512 threads = 8 waves (2M x 4N). Per-wave output 128x64 = acc[8][4] f32x4.
// LDS: A,B each [2 buf][2 K-half][256 rows][32 k] bf16 = 64 KiB -> 128 KiB total.
// K-tile = 64 (2 halves of 32). Schedule per K-tile k (4 phases):
//   P1: reads (h0, m0-3 + B)      | stage Kh1(k+1)  (k>=1)
//   P2: reads (h0, m4-7)          |
//   P3: reads (h1, m0-3 + B)      | stage Kh0(k+2)
//   P4: reads (h1, m4-7)          | group-end: vmcnt(4) (vmcnt(0) at k==NT-2)
// Ledger invariant: at exit of group k only Kh0(k+2) (4 loads) is outstanding,
// so K-tile k+1 is fully landed before group k+1 reads it. WAR: each stage
// overwrites a slot whose readers finished >=1 barrier earlier.
#define PHASE(BUF, H, MH, STAGE_STMT) do {                                              \
    const int hb_ = ((BUF) * 2 + (H)) * 8192;                                           \
    short8 af_[4];                                                                      \
    _Pragma("unroll") for (int mq = 0; mq < 4; mq++)                                    \
      af_[mq] = *(const short8*)&Al[hb_ + abase + ((MH) * 4 + mq) * 512];               \
    if ((MH) == 0) {                                                                    \
      _Pragma("unroll") for (int n = 0; n < 4; n++)                                     \
        bf[n] = *(const short8*)&Bl[hb_ + bbase + n * 512];                             \
    }                                                                                   \
    STAGE_STMT;                                                                         \
    BARRIER;                                                                            \
    LGK0;                                                                               \
    __builtin_amdgcn_s_setprio(1);                                                      \
    _Pragma("unroll") for (int mq = 0; mq < 4; mq++)                                    \
    _Pragma("unroll") for (int n = 0; n < 4; n++)                                       \
      acc[(MH) * 4 + mq][n] =                                                           \
          __builtin_amdgcn_mfma_f32_16x16x32_bf16(af_[mq], bf[n], acc[(MH)*4+mq][n], 0, 0, 0); \
    __builtin_amdgcn_s_setprio(0);                                                      \
  } while (0)

template <int NT>
__device__ __forceinline__ void gemm256(unsigned short* Al, unsigned short* Bl,
                                        const unsigned short* __restrict__ A,
                                        const unsigned short* __restrict__ B,
                                        int Kst, f32x4 (&acc)[8][4]) {
  const int tid = threadIdx.x;
  const int wv = tid >> 6, lane = tid & 63, quad = lane >> 4, l15 = lane & 15;
  const int wm = wv >> 2, wn = wv & 3;
  // chunk swizzle (both-sides involution, rule 21): chunk (row,q) holds global
  // k-chunk q^(row&3); ds_read uses the same XOR -> 4-way max bank conflict.
  const int qsw = (lane & 3) ^ ((lane >> 2) & 3);     // staging source chunk
  const int qs8 = (quad ^ (l15 & 3)) * 8;             // frag read chunk
  const int abase = (wm * 128 + l15) * 32 + qs8;
  const int bbase = (wn * 64 + l15) * 32 + qs8;

  auto stage = [&](int buf, int h, int kt) {
    const int kc = kt * 64 + h * 32 + qsw * 8;
#pragma unroll
    for (int i = 0; i < 2; i++) {
      int g = wv + i * 8;
      int row = g * 16 + (lane >> 2);
      ASYNC_COPY16(A + (size_t)row * Kst + kc, Al + ((buf * 2 + h) * 8192) + g * 512);
      ASYNC_COPY16(B + (size_t)row * Kst + kc, Bl + ((buf * 2 + h) * 8192) + g * 512);
    }
  };

  short8 bf[4];
  // prologue: K-tile 0 -> buf0, K-tile 1 -> buf1 (16 loads/wave)
  stage(0, 0, 0); stage(0, 1, 0); stage(1, 0, 1); stage(1, 1, 1);
  asm volatile("s_waitcnt vmcnt(8)" ::: "memory");  // K-tile 0 landed
  BARRIER; SCHEDB;

  for (int k = 0; k < NT; k++) {
    const int cur = k & 1;
    PHASE(cur, 0, 0, { if (k >= 1 && k + 1 < NT) stage((k + 1) & 1, 1, k + 1); });
    BARRIER; SCHEDB;
    PHASE(cur, 0, 1, {});
    BARRIER; SCHEDB;
    PHASE(cur, 1, 0, { if (k + 2 < NT) stage(cur, 0, k + 2); });
    BARRIER; SCHEDB;
    PHASE(cur, 1, 1, {});
    if (k < NT - 2)       asm volatile("s_waitcnt vmcnt(4)" ::: "memory");
    else if (k == NT - 2) asm volatile("s_waitcnt vmcnt(0)" ::: "memory");
    BARRIER; SCHEDB;
  }
}

// ---------------- pred GEMM: pred = ct @ Wk^T + Wk_b, M=N=4096, K=512 ----------------
// grid 256 (16x16 tiles of 256), 512 threads. Epilogue bounces C through LDS
// for fully coalesced bf16 writes in pred's [t][w][a][c] layout.
__global__ __launch_bounds__(512, 2) void pred_gemm(const unsigned short* __restrict__ A,
                                                    const unsigned short* __restrict__ Bt,
                                                    const float* __restrict__ bias,
                                                    unsigned short* __restrict__ pred) {
  __shared__ unsigned short Al[32768];
  __shared__ unsigned short Bl[32768];
  const int tid = threadIdx.x;
  const int wv = tid >> 6, lane = tid & 63, quad = lane >> 4, l15 = lane & 15;
  const int wm = wv >> 2, wn = wv & 3;
  const int M0 = (blockIdx.x >> 4) * 256, N0 = (blockIdx.x & 15) * 256;

  f32x4 acc[8][4];
#pragma unroll
  for (int m = 0; m < 8; m++)
#pragma unroll
    for (int n = 0; n < 4; n++) acc[m][n] = (f32x4){0.f, 0.f, 0.f, 0.f};

  gemm256<8>(Al, Bl, A + (size_t)M0 * 512, Bt + (size_t)N0 * 512, 512, acc);

  // epilogue: acc -> LDS (bf16, [256][256] split across Al/Bl) -> coalesced write
  float bvs[4];
#pragma unroll
  for (int n = 0; n < 4; n++) bvs[n] = bias[N0 + wn * 64 + n * 16 + l15];
  unsigned short* cstash = wm ? Bl : Al;
#pragma unroll
  for (int m = 0; m < 8; m++)
#pragma unroll
    for (int n = 0; n < 4; n++) {
      int cc = wn * 64 + n * 16 + l15;
#pragma unroll
      for (int r = 0; r < 4; r++) {
        int rl = (m * 16 + quad * 4 + r);  // 0..127 within wm-half
        cstash[rl * 256 + cc] = f2bf(acc[m][n][r] + bvs[n]);
      }
    }
  BARRIER;
  const int tq = N0 >> 8, a0 = M0 >> 3;
  for (int idx = tid; idx < 256 * 32; idx += 512) {
    int rl = idx >> 5, seg = idx & 31;
    short8 v = *(const short8*)((rl < 128 ? Al : Bl) + (rl & 127) * 256 + seg * 8);
    int a = a0 + (rl >> 3), w_ = rl & 7;
    *(short8*)&pred[(((size_t)tq * 8 + w_) * 512 + a) * 256 + seg * 8] = v;
  }
}

// ---------------- scores GEMM (256-tile 8-phase) + exp-sum/diag epilogue ----------------
// grid 512 = 128 tw x (2 rowblk x 2 colblk), XCD-swizzled (16 consecutive tw per XCD).
__global__ __launch_bounds__(512, 2) void scores_gemm(const unsigned short* __restrict__ F,
                                                      const unsigned short* __restrict__ pred,
                                                      const int* __restrict__ tsp,
                                                      float* __restrict__ rowsum_p,
                                                      float* __restrict__ diagv) {
  __shared__ unsigned short Al[32768];
  __shared__ unsigned short Bl[32768];
  const int tid = threadIdx.x;
  const int wv = tid >> 6, lane = tid & 63, quad = lane >> 4, l15 = lane & 15;
  const int wm = wv >> 2, wn = wv & 3;
  const int swz = (blockIdx.x & 7) * 64 + (blockIdx.x >> 3);  // bijective, 512%8==0
  const int tw = swz >> 2, rb = (swz >> 1) & 1, cb = swz & 1;
  const int t = tw >> 3, w_ = tw & 7;
  const int ts = tsp[0];
  const int lmin = min(ts + 1, L_SEQ - W_WIN);
  const int lp = min(ts + 1 + t, L_SEQ - W_WIN) + w_ - lmin;
  const unsigned short* A = F + (size_t)lp * (B_SZ * C_CH) + (size_t)rb * 256 * C_CH;
  const unsigned short* Bt = pred + (size_t)tw * (B_SZ * C_CH) + (size_t)cb * 256 * C_CH;

  f32x4 acc[8][4];
#pragma unroll
  for (int m = 0; m < 8; m++)
#pragma unroll
    for (int n = 0; n < 4; n++) acc[m][n] = (f32x4){0.f, 0.f, 0.f, 0.f};

  gemm256<4>(Al, Bl, A, Bt, 256, acc);

  // per-row partial sum of exp over this wave's 64 cols -> direct store (no atomics)
#pragma unroll
  for (int m = 0; m < 8; m++) {
#pragma unroll
    for (int r = 0; r < 4; r++) {
      float e = 0.f;
#pragma unroll
      for (int n = 0; n < 4; n++) e += __expf(acc[m][n][r] - NCE_SHIFT);
      e += __shfl_xor(e, 1);
      e += __shfl_xor(e, 2);
      e += __shfl_xor(e, 4);
      e += __shfl_xor(e, 8);
      if (l15 == 0) {
        int b = rb * 256 + wm * 128 + m * 16 + quad * 4 + r;
        rowsum_p[((size_t)tw * 8 + cb * 4 + wn) * B_SZ + b] = e;
      }
    }
  }
  if (rb == cb) {
#pragma unroll
    for (int m = 0; m < 8; m++)
#pragma unroll
      for (int n = 0; n < 4; n++)
#pragma unroll
        for (int r = 0; r < 4; r++) {
          int d = wm * 128 + m * 16 + quad * 4 + r - wn * 64 - n * 16;
          if (d == l15) {
            int b = rb * 256 + wm * 128 + m * 16 + quad * 4 + r;
            diagv[(size_t)tw * B_SZ + b] = acc[m][n][r];
          }
        }
  }
}

// ---------------- h1 GEMM (old m97 structure): M=4096, N=128, K=512 + BN stage-1 ----------------
__global__ __launch_bounds__(256) void gemm_h1(const unsigned short* __restrict__ A,
                                               const unsigned short* __restrict__ Bt,
                                               const float* __restrict__ bias,
                                               float* __restrict__ outf,
                                               float* __restrict__ bnp1,
                                               float* __restrict__ bnp2, int K) {
  __shared__ __align__(16) unsigned short As[128 * 64];
  __shared__ __align__(16) unsigned short Bs[128 * 64];
  const int tid = threadIdx.x;
  const int wv = tid >> 6, lane = tid & 63, quad = lane >> 4, l15 = lane & 15;
  const int wm = wv >> 1, wn = wv & 1;
  const int M0 = blockIdx.x * 128, N0 = 0;

  f32x4 acc[4][4];
#pragma unroll
  for (int i = 0; i < 4; i++)
#pragma unroll
    for (int j = 0; j < 4; j++) acc[i][j] = (f32x4){0.f, 0.f, 0.f, 0.f};

  for (int k0 = 0; k0 < K; k0 += 64) {
#pragma unroll
    for (int i = 0; i < 4; i++) {
      int chunk = (i * 4 + wv) * 64 + lane;
      int row = chunk >> 3, off = chunk & 7;
      ASYNC_COPY16(A + (size_t)(M0 + row) * K + k0 + off * 8, &As[(size_t)(i * 4 + wv) * 512]);
      ASYNC_COPY16(Bt + (size_t)(N0 + row) * K + k0 + off * 8, &Bs[(size_t)(i * 4 + wv) * 512]);
    }
    __syncthreads();
#pragma unroll
    for (int kk = 0; kk < 64; kk += 32) {
      short8 af[4], bfr[4];
#pragma unroll
      for (int i = 0; i < 4; i++)
        af[i] = *(const short8*)&As[(wm * 64 + i * 16 + l15) * 64 + kk + quad * 8];
#pragma unroll
      for (int j = 0; j < 4; j++)
        bfr[j] = *(const short8*)&Bs[(wn * 64 + j * 16 + l15) * 64 + kk + quad * 8];
#pragma unroll
      for (int i = 0; i < 4; i++)
#pragma unroll
        for (int j = 0; j < 4; j++)
          acc[i][j] = __builtin_amdgcn_mfma_f32_16x16x32_bf16(af[i], bfr[j], acc[i][j], 0, 0, 0);
    }
    __syncthreads();
  }

  float st1[4], st2[4];
#pragma unroll
  for (int j = 0; j < 4; j++) { st1[j] = 0.f; st2[j] = 0.f; }
#pragma unroll
  for (int i = 0; i < 4; i++) {
    int rbase = M0 + wm * 64 + i * 16 + quad * 4;
#pragma unroll
    for (int j = 0; j < 4; j++) {
      int cc = wn * 64 + j * 16 + l15;
      float bv = bias[cc];
#pragma unroll
      for (int r = 0; r < 4; r++) {
        int rr = rbase + r;
        float v = acc[i][j][r] + bv;
        outf[(size_t)rr * 128 + cc] = v;
        st1[j] += v;
        st2[j] += v * v;
      }
    }
  }
  // BN stage-1: reduce per-column sums within block, one atomic per column
  __shared__ float red1[2][128], red2[2][128];
#pragma unroll
  for (int j = 0; j < 4; j++) {
    float a1 = st1[j], a2 = st2[j];
    a1 += __shfl_xor(a1, 16); a1 += __shfl_xor(a1, 32);
    a2 += __shfl_xor(a2, 16); a2 += __shfl_xor(a2, 32);
    if (quad == 0) {
      red1[wm][wn * 64 + j * 16 + l15] = a1;
      red2[wm][wn * 64 + j * 16 + l15] = a2;
    }
  }
  __syncthreads();
  if (tid < 128) {
    atomicAdd(&bnp1[tid], red1[0][tid] + red1[1][tid]);
    atomicAdd(&bnp2[tid], red2[0][tid] + red2[1][tid]);
  }
}

// ---------------- nce reduction over 65536 rows (fused final sum via atomic) ----------------
__global__ __launch_bounds__(256) void nce_rows(const float* __restrict__ rowsum_p,
                                                const float* __restrict__ diagv,
                                                float* __restrict__ out) {
  int gid = blockIdx.x * 256 + threadIdx.x;  // 16384 threads
  float s = 0.f;
  for (int i = gid; i < 65536; i += 16384) {
    int tw = i >> 9, b = i & 511;
    float rs = 0.f;
#pragma unroll
    for (int p = 0; p < 8; p++) rs += rowsum_p[((size_t)tw * 8 + p) * B_SZ + b];
    s += logf(rs) + NCE_SHIFT - diagv[i];  // = -logp_diag
  }
#pragma unroll
  for (int off = 1; off < 64; off <<= 1) s += __shfl_xor(s, off);
  __shared__ float r[4];
  if ((threadIdx.x & 63) == 0) r[threadIdx.x >> 6] = s;
  __syncthreads();
  if (threadIdx.x == 0)
    atomicAdd(out, (r[0] + r[1] + r[2] + r[3]) * (1.f / 65536.f));
}

// ---------------- BN-finalize + apply + ReLU + GEMM2 -> proj (fp32, register-tiled) ----------------
__global__ __launch_bounds__(256) void proj2(const float* __restrict__ h1,
                                             const float* __restrict__ bnp1,
                                             const float* __restrict__ bnp2,
                                             const float* __restrict__ g,
                                             const float* __restrict__ bta,
                                             const float* __restrict__ pw2,
                                             const float* __restrict__ pb2,
                                             float* __restrict__ out) {
  __shared__ float hsT[128][68];
  __shared__ float pw2T[128][68];
  __shared__ float scs[128], shs[128];
  const int tid = threadIdx.x;
  for (int idx = tid; idx < 64 * 128; idx += 256) {
    int oc = idx >> 7, k = idx & 127;
    pw2T[k][oc] = pw2[idx];
  }
  if (tid < 128) {
    float mean = bnp1[tid] * (1.f / 4096.f);
    float var = bnp2[tid] * (1.f / 4096.f) - mean * mean;  // biased (BN train)
    float scale = g[tid] * rsqrtf(var + 1e-5f);
    scs[tid] = scale;
    shs[tid] = bta[tid] - mean * scale;
  }
  __syncthreads();
  const int r0 = blockIdx.x * 64;
  for (int idx = tid; idx < 64 * 128; idx += 256) {
    int r = idx >> 7, k = idx & 127;
    float v = h1[(size_t)(r0 + r) * 128 + k];
    hsT[k][r] = fmaxf(v * scs[k] + shs[k], 0.f);
  }
  __syncthreads();
  const int tx = tid & 15, ty = tid >> 4;
  float acc[4][4] = {};
  for (int k = 0; k < 128; k++) {
    f32x4 hv = *(const f32x4*)&hsT[k][ty * 4];
    f32x4 wv = *(const f32x4*)&pw2T[k][tx * 4];
#pragma unroll
    for (int i = 0; i < 4; i++)
#pragma unroll
      for (int j = 0; j < 4; j++) acc[i][j] += hv[i] * wv[j];
  }
#pragma unroll
  for (int i = 0; i < 4; i++) {
    int rr = r0 + ty * 4 + i;
#pragma unroll
    for (int j = 0; j < 4; j++)
      out[(size_t)rr * 64 + tx * 4 + j] = acc[i][j] + pb2[tx * 4 + j];
  }
}

extern "C" void kernel_launch(void* const* d_in, const int* in_sizes, int n_in,
                              void* d_out, int out_size, void* d_ws, size_t ws_size,
                              hipStream_t stream) {
  const float* features = (const float*)d_in[0];
  const float* c_t      = (const float*)d_in[1];
  const float* Wk_w     = (const float*)d_in[2];
  const float* Wk_b     = (const float*)d_in[3];
  const float* pw1      = (const float*)d_in[4];
  const float* pb1      = (const float*)d_in[5];
  const float* bn_gamma = (const float*)d_in[6];
  const float* bn_beta  = (const float*)d_in[7];
  const float* pw2      = (const float*)d_in[8];
  const float* pb2      = (const float*)d_in[9];
  const int*   tsp      = (const int*)d_in[10];
  float* out = (float*)d_out;

  // workspace carve-up (~52 MB total)
  char* ws = (char*)d_ws;
  size_t off = 0;
  auto carve = [&](size_t bytes) { void* p = ws + off; off += (bytes + 255) & ~(size_t)255; return p; };
  unsigned short* ct_bf  = (unsigned short*)carve((size_t)4096 * 512 * 2);   // c_t bf16 [bw][h]
  unsigned short* wk_bf  = (unsigned short*)carve((size_t)4096 * 512 * 2);   // Wk bf16 [tc][h]
  unsigned short* pw1_bf = (unsigned short*)carve((size_t)128 * 512 * 2);
  unsigned short* F      = (unsigned short*)carve((size_t)NSLAB * 512 * 256 * 2);
  unsigned short* pred   = (unsigned short*)carve((size_t)16 * 8 * 512 * 256 * 2);
  float* h1       = (float*)carve((size_t)4096 * 128 * 4);
  float* bnp1     = (float*)carve((size_t)128 * 4);
  float* bnp2     = (float*)carve((size_t)128 * 4);
  float* rowsum_p = (float*)carve((size_t)128 * 8 * 512 * 4);
  float* diagv    = (float*)carve((size_t)65536 * 4);

  prep<<<4161, 256, 0, stream>>>(c_t, Wk_w, pw1, ct_bf, wk_bf, pw1_bf, bnp1, bnp2, out);
  build_slabs2<<<512, 256, 0, stream>>>(features, F, tsp);

  // pred = ct @ Wk^T + Wk_b  (M=N=4096, K=512), 256-tile 8-phase
  pred_gemm<<<256, 512, 0, stream>>>(ct_bf, wk_bf, Wk_b, pred);
  // h1 = ct2d @ pw1^T + pb1  (M=4096, N=128, K=512) + BN stage-1 partials
  gemm_h1<<<32, 256, 0, stream>>>(ct_bf, pw1_bf, pb1, h1, bnp1, bnp2, 512);

  scores_gemm<<<512, 512, 0, stream>>>(F, pred, tsp, rowsum_p, diagv);
  nce_rows<<<64, 256, 0, stream>>>(rowsum_p, diagv, out);

  proj2<<<64, 256, 0, stream>>>(h1, bnp1, bnp2, bn_gamma, bn_beta, pw2, pb2, out + 1);
}